// Round 23
// baseline (239.776 us; speedup 1.0000x reference)
//
#include <hip/hip_runtime.h>

typedef __attribute__((ext_vector_type(4))) float        f32x4;
typedef __attribute__((ext_vector_type(4))) unsigned int u32x4;
typedef __attribute__((ext_vector_type(8))) short        bf16x8;

__device__ __forceinline__ short bf16_rne(float f) {
    unsigned int u = __float_as_uint(f);
    u += 0x7FFFu + ((u >> 16) & 1u);
    return (short)(u >> 16);
}

// G=16, in_g=out_g=64. rows-per-group = 32768, total rows = 524288.
// Row r: 64 contiguous floats of x; group g = r>>15.
// out[(g*64+o)*32768 + (r & 32767)].
// Wave: 64 consecutive rows = 4 tiles of 16 rows. 8192 waves = 2048 blocks x 4.
// NUMERICS: R1's validated path (absmax 0.031): A = bf16(xhat*gamma+beta),
// B = bf16(W), bias in fp32 epilogue.
// STORES: sc1+nt (aux=18) bypasses cache RMW entirely — WRITE = exactly |out|
// for end-burst (R18), per-tile scattered (R22), any geometry. Compiler-
// tracked form: __builtin_amdgcn_raw_buffer_store_b128 + make_buffer_rsrc.
// R23 THEORY: kernel sits on the VGPR-64 residency cliff (waves/SIMD: 8 at
// <=64, 4 at 65..128). R18=84 VGPR. Halve the deferral to vout[2][4]
// (pair-stores mid-kernel are safe+clean now) + launch_bounds(256,8) to push
// the allocator under 64 -> double residency ceiling.
// FAILED AVENUES (do not retry): persistence (R11/R16/R17); 2-deep prefetch
// (R13/R14); channel-split waves (R15); LDS epilogue (R8); nt-without-sc1
// (R4/R6/R7); raw asm stores mid-loop (R19: VGPR-recycle corruption);
// per-tile immediate buffer stores (R22: +8 VGPR, occupancy -8pt).

__global__ __launch_bounds__(256, 8)
void gln_mfma_kernel(const float* __restrict__ x,
                     const float* __restrict__ gamma,
                     const float* __restrict__ beta,
                     const float* __restrict__ W,
                     const float* __restrict__ bias,
                     float* __restrict__ out)
{
    const int tid  = threadIdx.x;
    const int lane = tid & 63;
    const int w    = blockIdx.x * 4 + (tid >> 6);   // 0..8191
    const int g    = w >> 9;                         // 16 groups, 512 waves each
    const int rr0  = (w & 511) << 6;                 // row-in-group base (64 rows)

    const int l15 = lane & 15;
    const int l4  = lane >> 4;      // 0..3
    const int ks  = l4 * 8;         // k-slice base within a 32-wide K chunk

    // ---- buffer resource over the whole out array (raw, bounds-check off) ----
    __amdgpu_buffer_rsrc_t srd =
        __builtin_amdgcn_make_buffer_rsrc((void*)out, (short)0,
                                          (int)0xFFFFFFFF, 0x00020000);

    // ---- B fragments: lane elem j = W[g][ot*16+l15][kc*32+ks+j] ----
    bf16x8 bfrag[4][2];
    {
        const float* Wg = W + (size_t)(g * 64) * 64;
        #pragma unroll
        for (int ot = 0; ot < 4; ++ot) {
            const float* wrow = Wg + (size_t)(ot * 16 + l15) * 64;
            #pragma unroll
            for (int kc = 0; kc < 2; ++kc) {
                f32x4 w0 = *(const f32x4*)(wrow + kc * 32 + ks);
                f32x4 w1 = *(const f32x4*)(wrow + kc * 32 + ks + 4);
                bf16x8 f;
                #pragma unroll
                for (int j = 0; j < 4; ++j) { f[j] = bf16_rne(w0[j]); f[j + 4] = bf16_rne(w1[j]); }
                bfrag[ot][kc] = f;
            }
        }
    }

    // ---- gamma/beta for this lane's 16 k positions ----
    float gk[16], bk[16];
    {
        const float* gp = gamma + g * 64;
        const float* bp = beta  + g * 64;
        #pragma unroll
        for (int kc = 0; kc < 2; ++kc) {
            f32x4 g0 = *(const f32x4*)(gp + kc * 32 + ks);
            f32x4 g1 = *(const f32x4*)(gp + kc * 32 + ks + 4);
            f32x4 b0 = *(const f32x4*)(bp + kc * 32 + ks);
            f32x4 b1 = *(const f32x4*)(bp + kc * 32 + ks + 4);
            #pragma unroll
            for (int j = 0; j < 4; ++j) {
                gk[kc * 8 + j] = g0[j]; gk[kc * 8 + 4 + j] = g1[j];
                bk[kc * 8 + j] = b0[j]; bk[kc * 8 + 4 + j] = b1[j];
            }
        }
    }

    float bo[4];
    #pragma unroll
    for (int ot = 0; ot < 4; ++ot) bo[ot] = bias[g * 64 + ot * 16 + l15];

    const float* xg = x + (size_t)g * 32768 * 64;
    // out element-offset base: channel (g*64 + ot*16 + l15), col rr0 + t*16 + l4*4
    const int obase = (g * 64 + l15) * 32768 + rr0 + l4 * 4;

    // ---- main loop: 2 pairs of 16-row tiles, 1-deep register prefetch ----
    f32x4 buf[2][4];
    {
        const float* rowp = xg + (size_t)(rr0 + l15) * 64;
        buf[0][0] = *(const f32x4*)(rowp + ks);
        buf[0][1] = *(const f32x4*)(rowp + ks + 4);
        buf[0][2] = *(const f32x4*)(rowp + 32 + ks);
        buf[0][3] = *(const f32x4*)(rowp + 32 + ks + 4);
    }

    #pragma unroll
    for (int p = 0; p < 2; ++p) {
        f32x4 vout[2][4];               // [tile-in-pair][ot]

        #pragma unroll
        for (int ti = 0; ti < 2; ++ti) {
            const int t = p * 2 + ti;
            if (t + 1 < 4) {
                const float* rowp = xg + (size_t)(rr0 + (t + 1) * 16 + l15) * 64;
                buf[(t + 1) & 1][0] = *(const f32x4*)(rowp + ks);
                buf[(t + 1) & 1][1] = *(const f32x4*)(rowp + ks + 4);
                buf[(t + 1) & 1][2] = *(const f32x4*)(rowp + 32 + ks);
                buf[(t + 1) & 1][3] = *(const f32x4*)(rowp + 32 + ks + 4);
            }

            // LN stats over the row (4 lanes share a row: xor 16, 32)
            float s = 0.f, s2 = 0.f;
            #pragma unroll
            for (int i = 0; i < 4; ++i) {
                #pragma unroll
                for (int j = 0; j < 4; ++j) {
                    float v = buf[t & 1][i][j];
                    s += v; s2 += v * v;
                }
            }
            s  += __shfl_xor(s, 16, 64);  s  += __shfl_xor(s, 32, 64);
            s2 += __shfl_xor(s2, 16, 64); s2 += __shfl_xor(s2, 32, 64);
            const float mu   = s * (1.0f / 64.0f);
            const float var  = s2 * (1.0f / 64.0f) - mu * mu;
            const float rstd = rsqrtf(var + 1e-6f);

            // normalize + affine -> A fragments (bf16)   [R1 numerics]
            bf16x8 a0, a1;
            #pragma unroll
            for (int j = 0; j < 8; ++j) {
                float c1 = rstd * gk[j];
                float v  = buf[t & 1][j >> 2][j & 3] * c1 + (bk[j] - mu * c1);
                a0[j] = bf16_rne(v);
            }
            #pragma unroll
            for (int j = 0; j < 8; ++j) {
                float c1 = rstd * gk[8 + j];
                float v  = buf[t & 1][2 + (j >> 2)][j & 3] * c1 + (bk[8 + j] - mu * c1);
                a1[j] = bf16_rne(v);
            }

            #pragma unroll
            for (int ot = 0; ot < 4; ++ot) {
                f32x4 acc = {0.f, 0.f, 0.f, 0.f};
                acc = __builtin_amdgcn_mfma_f32_16x16x32_bf16(a0, bfrag[ot][0], acc, 0, 0, 0);
                acc = __builtin_amdgcn_mfma_f32_16x16x32_bf16(a1, bfrag[ot][1], acc, 0, 0, 0);
                #pragma unroll
                for (int q = 0; q < 4; ++q) acc[q] += bo[ot];
                vout[ti][ot] = acc;
            }
        }

        // ---- pair store burst: compiler-tracked buffer stores, cpol NT|SC1 ----
        #pragma unroll
        for (int ot = 0; ot < 4; ++ot) {
            #pragma unroll
            for (int ti = 0; ti < 2; ++ti) {
                const int voff = (obase + ot * 16 * 32768 + (p * 2 + ti) * 16) * 4;
                u32x4 d = __builtin_bit_cast(u32x4, vout[ti][ot]);
                __builtin_amdgcn_raw_buffer_store_b128(d, srd, voff, 0, 18 /*NT|SC1*/);
            }
        }
    }
}

extern "C" void kernel_launch(void* const* d_in, const int* in_sizes, int n_in,
                              void* d_out, int out_size, void* d_ws, size_t ws_size,
                              hipStream_t stream) {
    const float* x     = (const float*)d_in[0];
    const float* gamma = (const float*)d_in[1];
    const float* beta  = (const float*)d_in[2];
    const float* W     = (const float*)d_in[3];
    const float* b     = (const float*)d_in[4];
    float* out = (float*)d_out;

    dim3 grid(2048), block(256);
    hipLaunchKernelGGL(gln_mfma_kernel, grid, block, 0, stream, x, gamma, beta, W, b, out);
}

// Round 25
// 53.182 us; speedup vs baseline: 4.5086x; 4.5086x over previous
//
#include <hip/hip_runtime.h>

typedef __attribute__((ext_vector_type(4))) float f32x4;
typedef __attribute__((ext_vector_type(8))) short bf16x8;

__device__ __forceinline__ short bf16_rne(float f) {
    unsigned int u = __float_as_uint(f);
    u += 0x7FFFu + ((u >> 16) & 1u);
    return (short)(u >> 16);
}

// G=16, in_g=out_g=64. rows-per-group = 32768, total rows = 524288.
// Row r: 64 contiguous floats of x; group g = r>>15.
// out[(g*64+o)*32768 + (r & 32767)].
// Wave: 64 consecutive rows = 4 tiles of 16 rows. 8192 waves = 2048 blocks x 4.
// == EXACT R18 STRUCTURE (champion, 53.6us) except store scope flags. ==
// NUMERICS: R1's validated path (absmax 0.031): A = bf16(xhat*gamma+beta),
// B = bf16(W) from GLOBAL loads, bias in fp32 epilogue.
// DO NOT restructure the bfrag source: two attempts (R2 gamma-fold, R24
// LDS-staged W) both failed numerics inexplicably despite on-paper identical
// fragment values. Global per-wave W loads are L1-served anyway (16KB <= 32KB
// L1, 4 waves/CU share Wg).
// STORES: sc1+nt = WRITE exactly |out|, no RMW (R18/R22 verified).
// R25 change: add sc0 -> (sc1,sc0)=system scope. Theory: sc1-only stores
// still ALLOCATE in L3; out (131MB) + x (134MB) = 265MB > 256MB L3 evicts
// half of x per replay (warm FETCH pinned at 66.7MB = x/2). System scope
// should bypass L3 allocation -> x fully L3-resident, FETCH -> ~0.
// FAILED AVENUES (do not retry): persistence (R11/R16/R17); 2-deep prefetch
// (R13/R14); channel-split waves (R15); LDS out-epilogue (R8); LDS W-staging
// (R24 numerics); gamma-fold into B (R2 numerics); nt-without-sc1 (R4/R6/R7);
// raw asm stores mid-loop (R19); per-tile buffer stores (R22);
// launch_bounds(256,8) (R23 spills).

__global__ __launch_bounds__(256, 2)
void gln_mfma_kernel(const float* __restrict__ x,
                     const float* __restrict__ gamma,
                     const float* __restrict__ beta,
                     const float* __restrict__ W,
                     const float* __restrict__ bias,
                     float* __restrict__ out)
{
    const int tid  = threadIdx.x;
    const int lane = tid & 63;
    const int w    = blockIdx.x * 4 + (tid >> 6);   // 0..8191
    const int g    = w >> 9;                         // 16 groups, 512 waves each
    const int rr0  = (w & 511) << 6;                 // row-in-group base (64 rows)

    const int l15 = lane & 15;
    const int l4  = lane >> 4;      // 0..3
    const int ks  = l4 * 8;         // k-slice base within a 32-wide K chunk

    // ---- B fragments: lane elem j = W[g][ot*16+l15][kc*32+ks+j] ----
    bf16x8 bfrag[4][2];
    {
        const float* Wg = W + (size_t)(g * 64) * 64;
        #pragma unroll
        for (int ot = 0; ot < 4; ++ot) {
            const float* wrow = Wg + (size_t)(ot * 16 + l15) * 64;
            #pragma unroll
            for (int kc = 0; kc < 2; ++kc) {
                f32x4 w0 = *(const f32x4*)(wrow + kc * 32 + ks);
                f32x4 w1 = *(const f32x4*)(wrow + kc * 32 + ks + 4);
                bf16x8 f;
                #pragma unroll
                for (int j = 0; j < 4; ++j) { f[j] = bf16_rne(w0[j]); f[j + 4] = bf16_rne(w1[j]); }
                bfrag[ot][kc] = f;
            }
        }
    }

    // ---- gamma/beta for this lane's 16 k positions ----
    float gk[16], bk[16];
    {
        const float* gp = gamma + g * 64;
        const float* bp = beta  + g * 64;
        #pragma unroll
        for (int kc = 0; kc < 2; ++kc) {
            f32x4 g0 = *(const f32x4*)(gp + kc * 32 + ks);
            f32x4 g1 = *(const f32x4*)(gp + kc * 32 + ks + 4);
            f32x4 b0 = *(const f32x4*)(bp + kc * 32 + ks);
            f32x4 b1 = *(const f32x4*)(bp + kc * 32 + ks + 4);
            #pragma unroll
            for (int j = 0; j < 4; ++j) {
                gk[kc * 8 + j] = g0[j]; gk[kc * 8 + 4 + j] = g1[j];
                bk[kc * 8 + j] = b0[j]; bk[kc * 8 + 4 + j] = b1[j];
            }
        }
    }

    float bo[4];
    #pragma unroll
    for (int ot = 0; ot < 4; ++ot) bo[ot] = bias[g * 64 + ot * 16 + l15];

    const float* xg = x   + (size_t)g * 32768 * 64;
    float* outg     = out + (size_t)g * 64 * 32768;

    // ---- main loop: 4 tiles of 16 rows, register double-buffered ----
    f32x4 buf[2][4];
    {
        const float* rowp = xg + (size_t)(rr0 + l15) * 64;
        buf[0][0] = *(const f32x4*)(rowp + ks);
        buf[0][1] = *(const f32x4*)(rowp + ks + 4);
        buf[0][2] = *(const f32x4*)(rowp + 32 + ks);
        buf[0][3] = *(const f32x4*)(rowp + 32 + ks + 4);
    }

    f32x4 vout[4][4];                   // [tile][ot] — all stores deferred

    #pragma unroll
    for (int t = 0; t < 4; ++t) {
        if (t + 1 < 4) {
            const float* rowp = xg + (size_t)(rr0 + (t + 1) * 16 + l15) * 64;
            buf[(t + 1) & 1][0] = *(const f32x4*)(rowp + ks);
            buf[(t + 1) & 1][1] = *(const f32x4*)(rowp + ks + 4);
            buf[(t + 1) & 1][2] = *(const f32x4*)(rowp + 32 + ks);
            buf[(t + 1) & 1][3] = *(const f32x4*)(rowp + 32 + ks + 4);
        }

        // LN stats over the row (4 lanes share a row: xor 16, 32)
        float s = 0.f, s2 = 0.f;
        #pragma unroll
        for (int i = 0; i < 4; ++i) {
            #pragma unroll
            for (int j = 0; j < 4; ++j) {
                float v = buf[t & 1][i][j];
                s += v; s2 += v * v;
            }
        }
        s  += __shfl_xor(s, 16, 64);  s  += __shfl_xor(s, 32, 64);
        s2 += __shfl_xor(s2, 16, 64); s2 += __shfl_xor(s2, 32, 64);
        const float mu   = s * (1.0f / 64.0f);
        const float var  = s2 * (1.0f / 64.0f) - mu * mu;
        const float rstd = rsqrtf(var + 1e-6f);

        // normalize + affine -> A fragments (bf16)   [R1 numerics]
        bf16x8 a0, a1;
        #pragma unroll
        for (int j = 0; j < 8; ++j) {
            float c1 = rstd * gk[j];
            float v  = buf[t & 1][j >> 2][j & 3] * c1 + (bk[j] - mu * c1);
            a0[j] = bf16_rne(v);
        }
        #pragma unroll
        for (int j = 0; j < 8; ++j) {
            float c1 = rstd * gk[8 + j];
            float v  = buf[t & 1][2 + (j >> 2)][j & 3] * c1 + (bk[8 + j] - mu * c1);
            a1[j] = bf16_rne(v);
        }

        #pragma unroll
        for (int ot = 0; ot < 4; ++ot) {
            f32x4 acc = {0.f, 0.f, 0.f, 0.f};
            acc = __builtin_amdgcn_mfma_f32_16x16x32_bf16(a0, bfrag[ot][0], acc, 0, 0, 0);
            acc = __builtin_amdgcn_mfma_f32_16x16x32_bf16(a1, bfrag[ot][1], acc, 0, 0, 0);
            #pragma unroll
            for (int q = 0; q < 4; ++q) acc[q] += bo[ot];
            vout[t][ot] = acc;
        }
    }

    // ---- epilogue (kernel end): per channel, FULL 256 B span,
    //      sc0+sc1+nt = system-scope non-temporal -> no L3 allocation ----
    #pragma unroll
    for (int ot = 0; ot < 4; ++ot) {
        float* base = outg + (size_t)(ot * 16 + l15) * 32768 + rr0 + l4 * 4;
        #pragma unroll
        for (int t = 0; t < 4; ++t) {
            float* dst = base + t * 16;
            asm volatile("global_store_dwordx4 %0, %1, off sc0 sc1 nt"
                         :: "v"(dst), "v"(vout[t][ot]) : "memory");
        }
    }
}

extern "C" void kernel_launch(void* const* d_in, const int* in_sizes, int n_in,
                              void* d_out, int out_size, void* d_ws, size_t ws_size,
                              hipStream_t stream) {
    const float* x     = (const float*)d_in[0];
    const float* gamma = (const float*)d_in[1];
    const float* beta  = (const float*)d_in[2];
    const float* W     = (const float*)d_in[3];
    const float* b     = (const float*)d_in[4];
    float* out = (float*)d_out;

    dim3 grid(2048), block(256);
    hipLaunchKernelGGL(gln_mfma_kernel, grid, block, 0, stream, x, gamma, beta, W, b, out);
}

// Round 27
// 49.041 us; speedup vs baseline: 4.8892x; 1.0844x over previous
//
#include <hip/hip_runtime.h>

typedef __attribute__((ext_vector_type(4))) float f32x4;
typedef __attribute__((ext_vector_type(8))) short bf16x8;

typedef const __attribute__((address_space(1))) float* gas1p;
typedef __attribute__((address_space(3))) float* las3p;

__device__ __forceinline__ short bf16_rne(float f) {
    unsigned int u = __float_as_uint(f);
    u += 0x7FFFu + ((u >> 16) & 1u);
    return (short)(u >> 16);
}

// G=16, in_g=out_g=64. rows-per-group = 32768, total rows = 524288.
// Row r: 64 contiguous floats of x; group g = r>>15.
// out[(g*64+o)*32768 + (r & 32767)].
// Wave: 64 consecutive rows = 4 tiles of 16 rows. 8192 waves = 2048 blocks x 4.
// NUMERICS: R1's validated path (absmax 0.031): A = bf16(xhat*gamma+beta),
// B = bf16(W) from global loads, bias in fp32 epilogue. x values reach LN
// bit-identical (staged through LDS untransformed).
// R26/R27 LEVER: latency/MLP. Register double-buffer = 1 tile in flight;
// compute (~200cy) x 4 waves/SIMD < HBM latency (~900cy). Fix: wave-private
// 3-slot LDS DMA pipeline (global_load_lds w16) with COUNTED vmcnt waits
// (literal-immediate asm; R26: builtin requires ICE). Depth 2-3 at zero VGPR
// cost, no barriers (wave-private slots -> no vmcnt(0) drain).
// XOR swizzle cl^(row&7): DMA write linear (required, m104) + read swizzled.
// Slot-0 refill is fenced by lgkmcnt(0)+sched_barrier (ds_reads must sample
// before DMA overwrite can land).
// STORES (FROZEN): defer vout[4][4]; per channel FULL 256-B span, 4 adjacent
// `global_store_dwordx4 sc0 sc1 nt` at KERNEL END (raw asm safe only there -
// R19). sc1+nt: WRITE = exactly |out| (R18/R22/R25).
// FAILED AVENUES (do not retry): persistence (R11/R16/R17); 2-deep REGISTER
// prefetch (R13/R14: VGPR->occupancy); channel-split (R15); LDS out-epilogue
// (R8); LDS W-staging (R24 numerics); gamma-fold (R2 numerics); nt w/o sc1
// (R4/R6/R7); asm stores mid-loop (R19); buffer-store per tile (R22);
// launch_bounds(256,8) (R23 spills); sc0 for L3 bypass (R25 neutral).

__global__ __launch_bounds__(256, 2)
void gln_mfma_kernel(const float* __restrict__ x,
                     const float* __restrict__ gamma,
                     const float* __restrict__ beta,
                     const float* __restrict__ W,
                     const float* __restrict__ bias,
                     float* __restrict__ out)
{
    __shared__ __align__(16) float xlds[4][3][1024];   // 4 waves x 3 slots x 4KB

    const int tid  = threadIdx.x;
    const int lane = tid & 63;
    const int wv   = tid >> 6;
    const int w    = blockIdx.x * 4 + wv;            // 0..8191
    const int g    = w >> 9;                         // 16 groups, 512 waves each
    const int rr0  = (w & 511) << 6;                 // row-in-group base (64 rows)

    const int l15 = lane & 15;
    const int l4  = lane >> 4;      // 0..3
    const int ks  = l4 * 8;         // k-slice base within a 32-wide K chunk

    const float* xg = x   + (size_t)g * 32768 * 64;
    float* outg     = out + (size_t)g * 64 * 32768;

    // issue tile t into slot s: 4 global_load_lds (w16), LDS linear by lane,
    // global source pre-swizzled so readback sector c is at stored c^(row&7).
    auto issue_tile = [&](int t, int s) {
        const float* tb = xg + (size_t)(rr0 + t * 16) * 64;
        #pragma unroll
        for (int j = 0; j < 4; ++j) {
            const int p   = j * 64 + lane;           // linear 16B-sector 0..255
            const int row = p >> 4;
            const int cl  = p & 15;
            const float* src = tb + row * 64 + ((cl ^ (row & 7)) << 2);
            __builtin_amdgcn_global_load_lds((gas1p)src,
                (las3p)(&xlds[wv][s][j * 256]), 16, 0, 0);
        }
    };

    // ---- prologue: issue tiles 0,1,2 (DMA latency hides under preamble) ----
    issue_tile(0, 0);
    issue_tile(1, 1);
    issue_tile(2, 2);
    __builtin_amdgcn_sched_barrier(0);

    // ---- B fragments: lane elem j = W[g][ot*16+l15][kc*32+ks+j] ----
    bf16x8 bfrag[4][2];
    {
        const float* Wg = W + (size_t)(g * 64) * 64;
        #pragma unroll
        for (int ot = 0; ot < 4; ++ot) {
            const float* wrow = Wg + (size_t)(ot * 16 + l15) * 64;
            #pragma unroll
            for (int kc = 0; kc < 2; ++kc) {
                f32x4 w0 = *(const f32x4*)(wrow + kc * 32 + ks);
                f32x4 w1 = *(const f32x4*)(wrow + kc * 32 + ks + 4);
                bf16x8 f;
                #pragma unroll
                for (int j = 0; j < 4; ++j) { f[j] = bf16_rne(w0[j]); f[j + 4] = bf16_rne(w1[j]); }
                bfrag[ot][kc] = f;
            }
        }
    }

    // ---- gamma/beta for this lane's 16 k positions ----
    float gk[16], bk[16];
    {
        const float* gp = gamma + g * 64;
        const float* bp = beta  + g * 64;
        #pragma unroll
        for (int kc = 0; kc < 2; ++kc) {
            f32x4 g0 = *(const f32x4*)(gp + kc * 32 + ks);
            f32x4 g1 = *(const f32x4*)(gp + kc * 32 + ks + 4);
            f32x4 b0 = *(const f32x4*)(bp + kc * 32 + ks);
            f32x4 b1 = *(const f32x4*)(bp + kc * 32 + ks + 4);
            #pragma unroll
            for (int j = 0; j < 4; ++j) {
                gk[kc * 8 + j] = g0[j]; gk[kc * 8 + 4 + j] = g1[j];
                bk[kc * 8 + j] = b0[j]; bk[kc * 8 + 4 + j] = b1[j];
            }
        }
    }

    float bo[4];
    #pragma unroll
    for (int ot = 0; ot < 4; ++ot) bo[ot] = bias[g * 64 + ot * 16 + l15];

    f32x4 vout[4][4];                   // [tile][ot] — all stores deferred
    const int swz = l15 & 7;

    #pragma unroll
    for (int t = 0; t < 4; ++t) {
        // wait for tile t's 4 DMAs (counted immediates; never drain younger tiles)
        if (t == 3)      asm volatile("s_waitcnt vmcnt(0)" ::: "memory");
        else if (t == 2) asm volatile("s_waitcnt vmcnt(4)" ::: "memory");
        else             asm volatile("s_waitcnt vmcnt(8)" ::: "memory");
        __builtin_amdgcn_sched_barrier(0);

        const float* sp = &xlds[wv][t % 3][0];
        f32x4 v0 = *(const f32x4*)(sp + l15 * 64 + (((2 * l4)     ^ swz) << 2));
        f32x4 v1 = *(const f32x4*)(sp + l15 * 64 + (((2 * l4 + 1) ^ swz) << 2));
        f32x4 v2 = *(const f32x4*)(sp + l15 * 64 + (((8 + 2 * l4) ^ swz) << 2));
        f32x4 v3 = *(const f32x4*)(sp + l15 * 64 + (((9 + 2 * l4) ^ swz) << 2));

        if (t == 0) {
            // slot 0 consumed; ensure the reads sampled before refill can land
            asm volatile("s_waitcnt lgkmcnt(0)" ::: "memory");
            __builtin_amdgcn_sched_barrier(0);
            issue_tile(3, 0);
        }

        // LN stats over the row (4 lanes share a row: xor 16, 32)
        float s = 0.f, s2 = 0.f;
        #pragma unroll
        for (int j = 0; j < 4; ++j) {
            s += v0[j] + v1[j] + v2[j] + v3[j];
            s2 += v0[j]*v0[j] + v1[j]*v1[j] + v2[j]*v2[j] + v3[j]*v3[j];
        }
        s  += __shfl_xor(s, 16, 64);  s  += __shfl_xor(s, 32, 64);
        s2 += __shfl_xor(s2, 16, 64); s2 += __shfl_xor(s2, 32, 64);
        const float mu   = s * (1.0f / 64.0f);
        const float var  = s2 * (1.0f / 64.0f) - mu * mu;
        const float rstd = rsqrtf(var + 1e-6f);

        // normalize + affine -> A fragments (bf16)   [R1 numerics]
        bf16x8 a0, a1;
        #pragma unroll
        for (int j = 0; j < 4; ++j) {
            float c1 = rstd * gk[j];
            a0[j]     = bf16_rne(v0[j] * c1 + (bk[j] - mu * c1));
            float c2 = rstd * gk[4 + j];
            a0[4 + j] = bf16_rne(v1[j] * c2 + (bk[4 + j] - mu * c2));
            float c3 = rstd * gk[8 + j];
            a1[j]     = bf16_rne(v2[j] * c3 + (bk[8 + j] - mu * c3));
            float c4 = rstd * gk[12 + j];
            a1[4 + j] = bf16_rne(v3[j] * c4 + (bk[12 + j] - mu * c4));
        }

        #pragma unroll
        for (int ot = 0; ot < 4; ++ot) {
            f32x4 acc = {0.f, 0.f, 0.f, 0.f};
            acc = __builtin_amdgcn_mfma_f32_16x16x32_bf16(a0, bfrag[ot][0], acc, 0, 0, 0);
            acc = __builtin_amdgcn_mfma_f32_16x16x32_bf16(a1, bfrag[ot][1], acc, 0, 0, 0);
            #pragma unroll
            for (int q = 0; q < 4; ++q) acc[q] += bo[ot];
            vout[t][ot] = acc;
        }
    }

    // ---- epilogue (kernel end): per channel, FULL 256 B span, sc0+sc1+nt ----
    #pragma unroll
    for (int ot = 0; ot < 4; ++ot) {
        float* base = outg + (size_t)(ot * 16 + l15) * 32768 + rr0 + l4 * 4;
        #pragma unroll
        for (int t = 0; t < 4; ++t) {
            float* dst = base + t * 16;
            asm volatile("global_store_dwordx4 %0, %1, off sc0 sc1 nt"
                         :: "v"(dst), "v"(vout[t][ot]) : "memory");
        }
    }
}

extern "C" void kernel_launch(void* const* d_in, const int* in_sizes, int n_in,
                              void* d_out, int out_size, void* d_ws, size_t ws_size,
                              hipStream_t stream) {
    const float* x     = (const float*)d_in[0];
    const float* gamma = (const float*)d_in[1];
    const float* beta  = (const float*)d_in[2];
    const float* W     = (const float*)d_in[3];
    const float* b     = (const float*)d_in[4];
    float* out = (float*)d_out;

    dim3 grid(2048), block(256);
    hipLaunchKernelGGL(gln_mfma_kernel, grid, block, 0, stream, x, gamma, beta, W, b, out);
}